// Round 5
// baseline (114.518 us; speedup 1.0000x reference)
//
#include <hip/hip_runtime.h>

#define T_LEN 256
#define N_LAYERS 128

__device__ __forceinline__ float ex2(float x) { return __builtin_amdgcn_exp2f(x); }
__device__ __forceinline__ float rcp1p(float e) { return __builtin_amdgcn_rcpf(1.0f + e); }

// wave_shr:1 (0x138): lane i <- lane i-1 within the wave (lane 0 keeps own). VALU pipe.
__device__ __forceinline__ float dpp_wave_shr1(float v) {
    int i = __float_as_int(v);
    return __int_as_float(__builtin_amdgcn_update_dpp(i, i, 0x138, 0xF, 0xF, false));
}
// wave_rol:1 (0x134): lane i <- lane (i+1)%64. x-conveyor toward lane 0.
__device__ __forceinline__ float dpp_wave_rol1(float v) {
    int i = __float_as_int(v);
    return __int_as_float(__builtin_amdgcn_update_dpp(i, i, 0x134, 0xF, 0xF, false));
}

// TWO waves, 128 lanes, ONE layer per lane (layer l = tid), software-pipelined
// wavefront: cell (l,t) runs at step s = t + l + wid  (wave 1 skewed +1 step).
//  - in-wave handoff: DPP wave_shr:1 of h (end of previous step). Exact.
//  - cross-wave handoff (layer 63 -> 64): all lanes store h to sh[tid] each
//    step; wave1 lane0 consumes sh[63] via a 2-register pipeline:
//    use(s) = read(s-2), so the LDS read has a FULL step (~130 cyc) of cover.
//    Skew arithmetic: consumer (l=64,D=1) at step s needs h63(t=s-65),
//    produced at step s-2, written end of s-2, read(s-2) after that step's
//    barrier. Exact.
//  - x reaches wave0 lane0 via a wave_rol:1 register conveyor (4 chunks).
//  - h-updates cndmask-gated on t-validity => ramp in/out leaves state exact.
// Per-SIMD issue halves vs the 1-wave version (6 transcendentals/step/wave),
// and the two waves run on different SIMDs in parallel.
__global__ __launch_bounds__(128, 1) void gru_stack_wavefront(
    const float* __restrict__ x,
    const float* __restrict__ w_ih,
    const float* __restrict__ w_hh,
    const float* __restrict__ b_ih,
    const float* __restrict__ b_hh,
    float* __restrict__ out)
{
    __shared__ float sh[128];
    const int tid  = threadIdx.x;        // 0..127 == layer index
    const int lane = tid & 63;
    const int wid  = tid >> 6;           // 0 or 1

    const float L1 = -1.4426950408889634f;   // -log2(e)   (sigmoid scale)
    const float L2 = -2.8853900817779268f;   // -2*log2(e) (tanh scale)

    // per-layer params (exp2-scaled)
    const float wi_r = L1 * w_ih[3 * tid + 0], wh_r = L1 * w_hh[3 * tid + 0];
    const float b_r  = L1 * (b_ih[3 * tid + 0] + b_hh[3 * tid + 0]);
    const float wi_z = L1 * w_ih[3 * tid + 1], wh_z = L1 * w_hh[3 * tid + 1];
    const float b_z  = L1 * (b_ih[3 * tid + 1] + b_hh[3 * tid + 1]);
    const float wi_n = L2 * w_ih[3 * tid + 2], bi_n = L2 * b_ih[3 * tid + 2];
    const float wh_n = L2 * w_hh[3 * tid + 2], bh_n = L2 * b_hh[3 * tid + 2];

    // x conveyor chunks (wave-local lane so wave1 stays in-bounds; its copy is unused)
    float xc0 = x[lane];
    float xc1 = x[lane + 64];
    float xc2 = x[lane + 128];
    float xc3 = x[lane + 192];

    float h = 0.0f;
    // h-dependent pre-activations (scaled), computed off the input chain
    float c_r = b_r, c_z = b_z, g_n = bh_n;

    float pend_use = 0.0f, pend_next = 0.0f;   // cross-wave pipeline: use(s)=read(s-2)
    const bool is_l0  = (lane == 0);
    const bool is_w0  = (wid == 0);
    const bool is_out = (tid == 127);

    sh[tid] = 0.0f;
    __syncthreads();

    int t = -tid - wid - 1;   // ++ at top of step -> t = s - tid - wid

    for (int blk = 0; blk < 6; ++blk) {
        float xq;
        if      (blk == 0) xq = xc0;
        else if (blk == 1) xq = xc1;
        else if (blk == 2) xq = xc2;
        else               xq = xc3;   // blocks 4,5: garbage, fully gated off

        #pragma unroll 8
        for (int k = 0; k < 64; ++k) {
            ++t;
            const bool valid = (unsigned)t < (unsigned)T_LEN;

            // input: lane0 of w0 <- x conveyor; lane0 of w1 <- LDS pipeline;
            // other lanes <- neighbor h via DPP (end of previous step)
            float shifted = dpp_wave_shr1(h);
            float alt = is_w0 ? xq : pend_use;        // wave-uniform select
            float in  = is_l0 ? alt : shifted;

            // GRU cell (exp2-scaled): r,z sigmoid; n tanh
            float u_r = fmaf(wi_r, in, c_r);
            float u_z = fmaf(wi_z, in, c_z);
            float u_n0 = fmaf(wi_n, in, bi_n);
            float r = rcp1p(ex2(u_r));
            float z = rcp1p(ex2(u_z));
            float u_n = fmaf(r, g_n, u_n0);
            float s_n = rcp1p(ex2(u_n));
            float n = fmaf(2.0f, s_n, -1.0f);
            float hn = fmaf(z, h - n, n);             // (1-z)*n + z*h
            h = valid ? hn : h;

            // precomputes for next step (off the input-critical chain)
            c_r = fmaf(wh_r, h, b_r);
            c_z = fmaf(wh_z, h, b_z);
            g_n = fmaf(wh_n, h, bh_n);

            if (is_out && valid) out[t] = h;          // layer 127 output

            // cross-wave handoff: publish h, then pipeline-read sh[63]
            sh[tid] = h;                              // unconditional: no exec-mask cost
            __syncthreads();                          // orders write(s) before read(s)
            float got = sh[63];                       // read(s), consumed at step s+2
            pend_use = pend_next;
            pend_next = got;

            xq = dpp_wave_rol1(xq);                   // conveyor: lane0 sees next x
        }
    }
}

extern "C" void kernel_launch(void* const* d_in, const int* in_sizes, int n_in,
                              void* d_out, int out_size, void* d_ws, size_t ws_size,
                              hipStream_t stream) {
    const float* x    = (const float*)d_in[0];  // [1,256]
    const float* w_ih = (const float*)d_in[1];  // [128,3,1]
    const float* w_hh = (const float*)d_in[2];  // [128,3,1]
    const float* b_ih = (const float*)d_in[3];  // [128,3]
    const float* b_hh = (const float*)d_in[4];  // [128,3]
    float* out = (float*)d_out;                 // [1,256]

    gru_stack_wavefront<<<1, 128, 0, stream>>>(x, w_ih, w_hh, b_ih, b_hh, out);
}